// Round 7
// baseline (379.599 us; speedup 1.0000x reference)
//
#include <hip/hip_runtime.h>
#include <stdint.h>
#include <stddef.h>

// ---------------------------------------------------------------------------
// MaskedMultiHeadAttn: B=2, S=2048, D=1024, H=16, DK=64, fp32 in/out.
// scores = K·Q^T (roles swapped), NO 1/sqrt(dk) scale, causal+pad mask.
// R16: launch-count + merge-traffic trim.
//      (1) k_merge folded into k_attn via atomic last-finisher: partial
//          chunks write fp32 O/rowsum, threadfence, atomicAdd per-pair
//          flag; the second arrival merges partner's partial (same-XCD
//          L2-resident) with its in-register accumulator and stores bf16.
//      (2) k_split_x + k_prep_w + flag-zero fused into one k_prep kernel
//          (grid-partitioned; preps overlap, flags re-zeroed per replay).
//      Pipeline: k_prep -> k_gemm_qkv -> k_attn -> k_gemm_o (4 launches).
// ---------------------------------------------------------------------------

typedef short bf16x8 __attribute__((ext_vector_type(8)));  // 8 bf16 = 4 VGPR
typedef float f32x4  __attribute__((ext_vector_type(4)));

__device__ __forceinline__ short f2bf(float f) {          // RNE
  union { float f; uint32_t u; } a; a.f = f;
  uint32_t r = a.u + 0x7fffu + ((a.u >> 16) & 1u);
  return (short)(r >> 16);
}
__device__ __forceinline__ float bf2f(short s) {
  union { uint32_t u; float f; } a; a.u = ((uint32_t)(uint16_t)s) << 16;
  return a.f;
}
__device__ __forceinline__ uint32_t pack2bf(float a, float b) {  // trunc pack
  union { float f; uint32_t u; } x, y; x.f = a; y.f = b;
  return (x.u >> 16) | (y.u & 0xffff0000u);
}
__device__ __forceinline__ float fast_exp2(float x) {
#if __has_builtin(__builtin_amdgcn_exp2f)
  return __builtin_amdgcn_exp2f(x);
#else
  return exp2f(x);
#endif
}
__device__ __forceinline__ void async16(const void* g, void* l) {
  __builtin_amdgcn_global_load_lds(
      (const __attribute__((address_space(1))) uint32_t*)g,
      (__attribute__((address_space(3))) uint32_t*)l, 16, 0, 0);
}
#define MFMA(a, b, c) __builtin_amdgcn_mfma_f32_16x16x32_bf16((a), (b), (c), 0, 0, 0)

// ---------------------------------------------------------------------------
// 1) fused prep: blocks [0,4096) cast x -> xhi bf16; blocks [4096,5120)
//    transpose W k/n fp32 -> bf16; block 5120 zeroes split-K flags.
// ---------------------------------------------------------------------------
__global__ void k_prep(const float* __restrict__ x, short* __restrict__ xhi,
                       const float* __restrict__ Wq, const float* __restrict__ Wk,
                       const float* __restrict__ Wv, const float* __restrict__ Wo,
                       short* __restrict__ whi, short* __restrict__ wo,
                       int* __restrict__ flags) {
  __shared__ float T[64][65];
  int bid = blockIdx.x;
  int t = threadIdx.x;
  if (bid < 4096) {
    int i = bid * 256 + t;
    float4 v = ((const float4*)x)[i];
    short4 h;
    h.x = f2bf(v.x);
    h.y = f2bf(v.y);
    h.z = f2bf(v.z);
    h.w = f2bf(v.w);
    ((short4*)xhi)[i] = h;
  } else if (bid < 5120) {
    int i = bid - 4096;
    int bx = i & 15, by = (i >> 4) & 15, z = i >> 8;
    const float* W = (z == 0) ? Wq : (z == 1) ? Wk : (z == 2) ? Wv : Wo;
    int n0 = bx * 64, k0 = by * 64;
    int rr = t >> 4, cc = (t & 15) * 4;
#pragma unroll
    for (int it = 0; it < 4; ++it) {
      int row = rr + it * 16;
      float4 v = *(const float4*)&W[(size_t)(k0 + row) * 1024 + n0 + cc];
      T[row][cc] = v.x; T[row][cc + 1] = v.y; T[row][cc + 2] = v.z; T[row][cc + 3] = v.w;
    }
    __syncthreads();
    short* oh = (z < 3) ? (whi + (size_t)z * 1048576) : wo;
#pragma unroll
    for (int it = 0; it < 4; ++it) {
      int nrow = rr + it * 16;
      short4 h4;
      h4.x = f2bf(T[cc + 0][nrow]);
      h4.y = f2bf(T[cc + 1][nrow]);
      h4.z = f2bf(T[cc + 2][nrow]);
      h4.w = f2bf(T[cc + 3][nrow]);
      *(short4*)&oh[(size_t)(n0 + nrow) * 1024 + k0 + cc] = h4;
    }
  } else {
    flags[t] = 0;                   // 512 pair flags
    flags[t + 256] = 0;
  }
}

// ---------------------------------------------------------------------------
// 2) fused QKV projection GEMM (plain bf16, dbuf, single barrier/k-step).
//    Q-proj scaled by LOG2E. Q/K path: operand-swapped MFMA -> short4
//    stores. Q writes hi only; K writes hi+lo. V path writes Vt TRANSPOSED.
// ---------------------------------------------------------------------------
__global__ __launch_bounds__(256, 3) void k_gemm_qkv(
    const short* __restrict__ xhi, const short* __restrict__ whi,
    const float* __restrict__ bq, const float* __restrict__ bk,
    const float* __restrict__ bv,
    short* __restrict__ Qhi, short* __restrict__ Qlo,
    short* __restrict__ Khi, short* __restrict__ Klo,
    short* __restrict__ Vt) {
  __shared__ short AH[2][4096];
  __shared__ short BH[2][4096];
  int tid = threadIdx.x;
  int bx = blockIdx.x;                 // 0..23 ; z = bx>>3 : 0=Q 1=K 2=V
  int m0 = blockIdx.y * 128;
  int n0g = bx * 128;
  int w = tid >> 6, lane = tid & 63, lr = lane & 15, lq = lane >> 4;
  int wm = w >> 1, wn = w & 1;
  int z = bx >> 3;
  f32x4 acc[4][4] = {};

  auto stage = [&](int ks, int pb) {
#pragma unroll
    for (int it = 0; it < 2; ++it) {
      int idx = it * 256 + tid;
      int row = idx >> 2, c = idx & 3;
      int cs = c ^ (row & 3);
      async16(xhi + (size_t)(m0 + row) * 1024 + ks * 32 + cs * 8, &AH[pb][idx * 8]);
      async16(whi + (size_t)(n0g + row) * 1024 + ks * 32 + cs * 8, &BH[pb][idx * 8]);
    }
  };

  stage(0, 0);
  int p = 0;
  int g = lq ^ (lr & 3);
  if (z == 2) {
    // ---- V path: original operand order (row-packed epilogue) ----
    for (int ks = 0; ks < 32; ++ks) {
      __syncthreads();
      if (ks < 31) stage(ks + 1, p ^ 1);
      const bf16x8* A8 = (const bf16x8*)AH[p];
      const bf16x8* B8 = (const bf16x8*)BH[p];
      bf16x8 af[4], bfr[4];
#pragma unroll
      for (int mt = 0; mt < 4; ++mt) af[mt] = A8[(wm * 64 + mt * 16 + lr) * 4 + g];
#pragma unroll
      for (int nt = 0; nt < 4; ++nt) bfr[nt] = B8[(wn * 64 + nt * 16 + lr) * 4 + g];
#pragma unroll
      for (int mt = 0; mt < 4; ++mt)
#pragma unroll
        for (int nt = 0; nt < 4; ++nt)
          acc[mt][nt] = MFMA(af[mt], bfr[nt], acc[mt][nt]);
      p ^= 1;
    }
    // V: write transposed Vt[(b*16+h)*64+dk][s], bias fused, short4 packs
#pragma unroll
    for (int nt = 0; nt < 4; ++nt) {
      int dg = (n0g & 1023) + wn * 64 + nt * 16 + lr;
      float bvv = bv[dg];
      int hh = dg >> 6, dk = dg & 63;
#pragma unroll
      for (int mt = 0; mt < 4; ++mt) {
        int row = m0 + wm * 64 + mt * 16 + lq * 4;
        int b_ = row >> 11, s_ = row & 2047;
        short4 pk;
        pk.x = f2bf(acc[mt][nt][0] + bvv);
        pk.y = f2bf(acc[mt][nt][1] + bvv);
        pk.z = f2bf(acc[mt][nt][2] + bvv);
        pk.w = f2bf(acc[mt][nt][3] + bvv);
        *(short4*)&Vt[(size_t)((b_ * 16 + hh) * 64 + dk) * 2048 + s_] = pk;
      }
    }
  } else {
    // ---- Q/K path: operand-swapped MFMA -> vectorized short4 epilogue ----
    for (int ks = 0; ks < 32; ++ks) {
      __syncthreads();
      if (ks < 31) stage(ks + 1, p ^ 1);
      const bf16x8* A8 = (const bf16x8*)AH[p];
      const bf16x8* B8 = (const bf16x8*)BH[p];
      bf16x8 af[4], bfr[4];
#pragma unroll
      for (int mt = 0; mt < 4; ++mt) af[mt] = A8[(wm * 64 + mt * 16 + lr) * 4 + g];
#pragma unroll
      for (int nt = 0; nt < 4; ++nt) bfr[nt] = B8[(wn * 64 + nt * 16 + lr) * 4 + g];
#pragma unroll
      for (int mt = 0; mt < 4; ++mt)
#pragma unroll
        for (int nt = 0; nt < 4; ++nt)
          acc[mt][nt] = MFMA(bfr[nt], af[mt], acc[mt][nt]);   // D^T fragment
      p ^= 1;
    }
    const float LOG2E = 1.44269504f;
    const float* bias = (z == 0) ? bq : bk;
    short* Ch = (z == 0) ? Qhi : Khi;
    short* Cl = (z == 0) ? Qlo : Klo;
#pragma unroll
    for (int mt = 0; mt < 4; ++mt) {
      int row = m0 + wm * 64 + mt * 16 + lr;
#pragma unroll
      for (int nt = 0; nt < 4; ++nt) {
        int colg = (n0g & 1023) + wn * 64 + nt * 16 + lq * 4;
        float4 b4 = *(const float4*)&bias[colg];
        float v0 = acc[mt][nt][0] + b4.x;
        float v1 = acc[mt][nt][1] + b4.y;
        float v2 = acc[mt][nt][2] + b4.z;
        float v3 = acc[mt][nt][3] + b4.w;
        if (z == 0) { v0 *= LOG2E; v1 *= LOG2E; v2 *= LOG2E; v3 *= LOG2E; }
        short4 hi4, lo4;
        hi4.x = f2bf(v0); lo4.x = f2bf(v0 - bf2f(hi4.x));
        hi4.y = f2bf(v1); lo4.y = f2bf(v1 - bf2f(hi4.y));
        hi4.z = f2bf(v2); lo4.z = f2bf(v2 - bf2f(hi4.z));
        hi4.w = f2bf(v3); lo4.w = f2bf(v3 - bf2f(hi4.w));
        size_t o = (size_t)row * 1024 + colg;
        *(short4*)&Ch[o] = hi4;
        if (z == 1) *(short4*)&Cl[o] = lo4;   // Qlo not needed
      }
    }
  }
}

// ---------------------------------------------------------------------------
// 3) O-projection GEMM: out = Obuf @ Wo^T + bo, fp32 out.
//    128x128 tiles, m97 structure; operand-swapped MFMA -> float4 stores.
// ---------------------------------------------------------------------------
__global__ __launch_bounds__(256, 3) void k_gemm_o(
    const short* __restrict__ Ab, const short* __restrict__ Bb,
    const float* __restrict__ bias, float* __restrict__ Cf) {
  __shared__ short AH[2][4096];
  __shared__ short BH[2][4096];
  int tid = threadIdx.x;
  int m0 = blockIdx.y * 128, n0 = blockIdx.x * 128;
  int w = tid >> 6, lane = tid & 63, lr = lane & 15, lq = lane >> 4;
  int wm = w >> 1, wn = w & 1;
  f32x4 acc[4][4] = {};

  auto stage = [&](int ks, int pb) {
#pragma unroll
    for (int it = 0; it < 2; ++it) {
      int idx = it * 256 + tid;
      int row = idx >> 2, c = idx & 3;
      int cs = c ^ (row & 3);
      async16(Ab + (size_t)(m0 + row) * 1024 + ks * 32 + cs * 8, &AH[pb][idx * 8]);
      async16(Bb + (size_t)(n0 + row) * 1024 + ks * 32 + cs * 8, &BH[pb][idx * 8]);
    }
  };

  stage(0, 0);
  int p = 0;
  int g = lq ^ (lr & 3);
  for (int ks = 0; ks < 32; ++ks) {
    __syncthreads();
    if (ks < 31) stage(ks + 1, p ^ 1);
    const bf16x8* A8 = (const bf16x8*)AH[p];
    const bf16x8* B8 = (const bf16x8*)BH[p];
    bf16x8 af[4], bfr[4];
#pragma unroll
    for (int mt = 0; mt < 4; ++mt) af[mt] = A8[(wm * 64 + mt * 16 + lr) * 4 + g];
#pragma unroll
    for (int nt = 0; nt < 4; ++nt) bfr[nt] = B8[(wn * 64 + nt * 16 + lr) * 4 + g];
#pragma unroll
    for (int mt = 0; mt < 4; ++mt)
#pragma unroll
      for (int nt = 0; nt < 4; ++nt)
        acc[mt][nt] = MFMA(bfr[nt], af[mt], acc[mt][nt]);     // D^T fragment
    p ^= 1;
  }

#pragma unroll
  for (int mt = 0; mt < 4; ++mt) {
    int row = m0 + wm * 64 + mt * 16 + lr;
#pragma unroll
    for (int nt = 0; nt < 4; ++nt) {
      int colg = n0 + wn * 64 + nt * 16 + lq * 4;
      float4 b4 = *(const float4*)&bias[colg];
      float4 o4;
      o4.x = acc[mt][nt][0] + b4.x;
      o4.y = acc[mt][nt][1] + b4.y;
      o4.z = acc[mt][nt][2] + b4.z;
      o4.w = acc[mt][nt][3] + b4.w;
      *(float4*)&Cf[(size_t)row * 1024 + colg] = o4;
    }
  }
}

// ---------------------------------------------------------------------------
// 4) flash attention, split-K chunked + atomic last-finisher merge.
//    Work item o (0..47) per bh:
//    o<16:            chunk0 of pair P=16+o, tiles [0,16), partial slot A.
//    o>=16, q=o-16:   lvl=q>>1 (trips 16-lvl);
//      q odd:  single pair P=15-lvl, tiles [0,P+1), direct output.
//      q even: chunk1 of pair P=31-lvl, tiles [16,P+1), partial slot B.
//    All trips <=16; 1536 blocks. Partial chunks write fp32 O/rowsum, then
//    threadfence + per-pair atomicAdd; second arrival merges partner's
//    partial (same bh => same XCD => L2-local) with its register O and
//    stores bf16. Inner loop identical to R15 2-term.
// ---------------------------------------------------------------------------
__global__ __launch_bounds__(256, 4) void k_attn(
    const short* __restrict__ Khi, const short* __restrict__ Klo,
    const short* __restrict__ Qhi, const short* __restrict__ Vt,
    const int* __restrict__ amask, short* __restrict__ Obuf,
    float* __restrict__ PA, float* __restrict__ PB,
    float* __restrict__ LA, float* __restrict__ LB,
    int* __restrict__ flags) {
  __shared__ short QH[2][4096];     // Q-proj tile hi: [j 64][d 64] swizzled
  __shared__ short VS[2][4096];     // V^T tile: [d 64][j 64] swizzled
  int tid = threadIdx.x;
  int bid = blockIdx.x;             // 0..1535
  int xcd = bid & 7, i2 = bid >> 3; // i2: 0..191
  int bh = xcd * 4 + (i2 & 3);      // 4 heads per XCD for L2 locality
  int o  = i2 >> 2;                 // work item 0..47 (LPT order)
  int P, t0, t1;
  bool partial, slotB = false;
  if (o < 16) {                     // chunk0, trips 16
    P = 16 + o; t0 = 0; t1 = 16; partial = true;
  } else {
    int q = o - 16, lvl = q >> 1;   // trips = 16 - lvl
    if (q & 1) {                    // single chunk, direct
      P = 15 - lvl; t0 = 0; t1 = P + 1; partial = false;
    } else {                        // chunk1
      P = 31 - lvl; t0 = 16; t1 = P + 1; partial = true; slotB = true;
    }
  }
  int b = bh >> 4, h = bh & 15;
  int w = tid >> 6, lane = tid & 63, lr = lane & 15, lq = lane >> 4;
  int band = 2 * P + (w >> 1);
  int rb0 = band * 32 + (w & 1) * 16;   // wave's 16-row chunk base (in s)

  // keys-role B-fragments (K-proj rows of this wave's chunk), hi+lo
  bf16x8 kh[2], kl[2];
  {
    size_t ra = ((size_t)(b * 2048 + rb0 + lr)) * 1024 + h * 64;
#pragma unroll
    for (int ks = 0; ks < 2; ++ks) {
      kh[ks] = *(const bf16x8*)(Khi + ra + ks * 32 + lq * 8);
      kl[ks] = *(const bf16x8*)(Klo + ra + ks * 32 + lq * 8);
    }
  }

  f32x4 O[4] = {};
  float ls = 0.f;
  int iq = rb0 + lr;                // this lane's query row (s index)
  int baddr0 = (((lq & 1) * 2) * 16 + lr) * 4;   // bpermute byte addrs
  int baddr1 = baddr0 + 64;

  auto stage = [&](int jt, int pb) {
    int j0 = jt * 64;
#pragma unroll
    for (int it = 0; it < 2; ++it) {
      int idx2 = it * 256 + tid;    // 0..511
      int rr = idx2 >> 3, c = idx2 & 7;
      int cs = c ^ (rr & 7);
      size_t gq = ((size_t)(b * 2048 + j0 + rr)) * 1024 + h * 64 + cs * 8;
      async16(Qhi + gq, &QH[pb][idx2 * 8]);
      size_t gv = ((size_t)(bh * 64 + rr)) * 2048 + j0 + cs * 8;
      async16(Vt + gv, &VS[pb][idx2 * 8]);
    }
  };

  stage(t0, 0);
  int p = 0;
  for (int t = t0; t < t1; ++t) {
    __syncthreads();                // buf p staged; buf p^1 free
    if (t + 1 < t1) stage(t + 1, p ^ 1);
    int j0 = t * 64;
    const bf16x8* Q8 = (const bf16x8*)QH[p];
    const bf16x8* V8 = (const bf16x8*)VS[p];

    // padding-mask fast path (wave-level)
    int av = amask[b * 2048 + j0 + lane];
    unsigned long long bal = __ballot(av != 0);
    bool allv = (bal == ~0ull);

    // ---- S^T: rows j (4 mt), cols q (lr). 2-term split. ----
    f32x4 s[4] = {};
#pragma unroll
    for (int mt = 0; mt < 4; ++mt) {
      int row = mt * 16 + lr;
#pragma unroll
      for (int ks = 0; ks < 2; ++ks) {
        int gi = row * 8 + ((ks * 4 + lq) ^ (row & 7));
        bf16x8 qa = Q8[gi];
        s[mt] = MFMA(qa, kh[ks], s[mt]);
        s[mt] = MFMA(qa, kl[ks], s[mt]);
      }
    }

    // ---- exp2 / masks / rowsum / pack ----
    bool diag = (t == P);           // pair's last tile (never true in chunk0)
    float pv[4][4];
#pragma unroll
    for (int mt = 0; mt < 4; ++mt)
#pragma unroll
      for (int r = 0; r < 4; ++r)
        pv[mt][r] = fast_exp2(s[mt][r]);
    if (diag) {
#pragma unroll
      for (int mt = 0; mt < 4; ++mt)
#pragma unroll
        for (int r = 0; r < 4; ++r)
          if (j0 + mt * 16 + lq * 4 + r > iq) pv[mt][r] = 0.f;
    }
    if (!allv) {
#pragma unroll
      for (int mt = 0; mt < 4; ++mt)
#pragma unroll
        for (int r = 0; r < 4; ++r)
          if (!((bal >> (mt * 16 + lq * 4 + r)) & 1)) pv[mt][r] = 0.f;
    }
    uint32_t pd[4][2];
#pragma unroll
    for (int mt = 0; mt < 4; ++mt) {
      ls += (pv[mt][0] + pv[mt][1]) + (pv[mt][2] + pv[mt][3]);
      pd[mt][0] = pack2bf(pv[mt][0], pv[mt][1]);
      pd[mt][1] = pack2bf(pv[mt][2], pv[mt][3]);
    }

    // ---- P^T -> A-frag via bpermute; PV ----
#pragma unroll
    for (int k2 = 0; k2 < 2; ++k2) {
      union { int i[4]; bf16x8 v; } pa;
#pragma unroll
      for (int dd = 0; dd < 4; ++dd) {
        int addr = (dd >> 1) ? baddr1 : baddr0;
        int v0 = __builtin_amdgcn_ds_bpermute(addr, (int)pd[k2 * 2 + 0][dd & 1]);
        int v1 = __builtin_amdgcn_ds_bpermute(addr, (int)pd[k2 * 2 + 1][dd & 1]);
        pa.i[dd] = (lq >> 1) ? v1 : v0;
      }
#pragma unroll
      for (int nt = 0; nt < 4; ++nt) {
        int row = nt * 16 + lr;
        bf16x8 vb = V8[row * 8 + ((k2 * 4 + lq) ^ (row & 7))];
        O[nt] = MFMA(pa.v, vb, O[nt]);
      }
    }
    p ^= 1;
  }

  // ---- epilogue: reduce rowsum over lq ----
  float tsum = ls;
  tsum += __shfl_xor(tsum, 16);
  tsum += __shfl_xor(tsum, 32);     // lane l: full rowsum of row rb0+(l&15)

  if (!partial) {
    float inv[4];
#pragma unroll
    for (int r = 0; r < 4; ++r) inv[r] = 1.0f / __shfl(tsum, lq * 4 + r, 64);
#pragma unroll
    for (int nt = 0; nt < 4; ++nt)
#pragma unroll
      for (int r = 0; r < 4; ++r) {
        int row = b * 2048 + rb0 + lq * 4 + r;
        int col = h * 64 + nt * 16 + lr;
        Obuf[(size_t)row * 1024 + col] = f2bf(O[nt][r] * inv[r]);
      }
  } else {
    // write unnormalized fp32 partial, then race for last-finisher merge
    float* PO = slotB ? PB : PA;
    float* PL = slotB ? LB : LA;
    const float* PO_o = slotB ? PA : PB;
    const float* PL_o = slotB ? LA : LB;
    int pairIdx = bh * 16 + (P - 16);       // 0..511
    int prb = pairIdx * 64 + w * 16;        // partial row base for this wave
#pragma unroll
    for (int nt = 0; nt < 4; ++nt)
#pragma unroll
      for (int r = 0; r < 4; ++r)
        PO[(size_t)(prb + lq * 4 + r) * 64 + nt * 16 + lr] = O[nt][r];
    if (lq == 0) PL[prb + lr] = tsum;
    __threadfence();                // release: partials visible device-wide
    __syncthreads();                // all waves' writes issued before flag
    __shared__ int oldSh;
    if (tid == 0) oldSh = atomicAdd(&flags[pairIdx], 1);
    __syncthreads();
    if (oldSh == 1) {
      __threadfence();              // acquire: partner's writes visible
      float osum = PL_o[prb + lr];  // partner rowsum for row lr
      float tot = tsum + osum;
      float inv[4];
#pragma unroll
      for (int r = 0; r < 4; ++r) inv[r] = 1.0f / __shfl(tot, lq * 4 + r, 64);
#pragma unroll
      for (int nt = 0; nt < 4; ++nt)
#pragma unroll
        for (int r = 0; r < 4; ++r) {
          float oo = O[nt][r] +
                     PO_o[(size_t)(prb + lq * 4 + r) * 64 + nt * 16 + lr];
          int row = b * 2048 + rb0 + lq * 4 + r;
          int col = h * 64 + nt * 16 + lr;
          Obuf[(size_t)row * 1024 + col] = f2bf(oo * inv[r]);
        }
    }
  }
}

// ---------------------------------------------------------------------------
// launcher
// ---------------------------------------------------------------------------
extern "C" void kernel_launch(void* const* d_in, const int* in_sizes, int n_in,
                              void* d_out, int out_size, void* d_ws, size_t ws_size,
                              hipStream_t stream) {
  const float* x  = (const float*)d_in[0];
  const int* amask = (const int*)d_in[1];
  const float* Wq = (const float*)d_in[2];
  const float* bq = (const float*)d_in[3];
  const float* Wk = (const float*)d_in[4];
  const float* bk = (const float*)d_in[5];
  const float* Wv = (const float*)d_in[6];
  const float* bv = (const float*)d_in[7];
  const float* Wo = (const float*)d_in[8];
  const float* bo = (const float*)d_in[9];

  char* ws = (char*)d_ws;
  const size_t MB = 1024 * 1024;
  short* xhi = (short*)(ws);             // 0..8MB; dead after qkv -> Obuf
  float* PA  = (float*)(ws + 8 * MB);    // 8..16MB: split-K partial O slot A
  short* whi = (short*)(ws + 16 * MB);   // 16..22 (q,k,v)
  float* LA  = (float*)(ws + 22 * MB);   // rowsum A (128KB)
  float* LB  = (float*)(ws + 23 * MB);   // rowsum B (128KB)
  int*  flags = (int*)(ws + 24 * MB);    // 512 pair flags (2KB)
  short* wo  = (short*)(ws + 26 * MB);   // 26..28
  short* Qhi = (short*)(ws + 28 * MB);
  float* PB  = (float*)(ws + 36 * MB);   // 36..44MB (dead Qlo region): slot B
  short* Qlo = (short*)(ws + 36 * MB);   // unused (kept for qkv signature)
  short* Khi = (short*)(ws + 44 * MB);
  short* Klo = (short*)(ws + 52 * MB);
  short* Vt  = (short*)(ws + 60 * MB);   // total 68MB
  short* Obuf = xhi;                     // xhi dead after qkv

  k_prep<<<5121, 256, 0, stream>>>(x, xhi, Wq, Wk, Wv, Wo, whi, wo, flags);
  k_gemm_qkv<<<dim3(24, 32), 256, 0, stream>>>(xhi, whi, bq, bk, bv,
                                               Qhi, Qlo, Khi, Klo, Vt);
  k_attn<<<1536, 256, 0, stream>>>(Khi, Klo, Qhi, Vt, amask, Obuf,
                                   PA, PB, LA, LB, flags);
  k_gemm_o<<<dim3(8, 32), 256, 0, stream>>>(Obuf, wo, bo, (float*)d_out);
}

// Round 8
// 201.878 us; speedup vs baseline: 1.8803x; 1.8803x over previous
//
#include <hip/hip_runtime.h>
#include <stdint.h>
#include <stddef.h>

// ---------------------------------------------------------------------------
// MaskedMultiHeadAttn: B=2, S=2048, D=1024, H=16, DK=64, fp32 in/out.
// scores = K·Q^T (roles swapped), NO 1/sqrt(dk) scale, causal+pad mask.
// R17: revert R16's atomic last-finisher merge (per-block device-scope
//      __threadfence on 8 non-coherent XCD L2s => continuous L2 flush,
//      k_attn 50->234us). Split-K partials go back through the explicit
//      k_merge kernel (the kernel boundary IS the one global fence).
//      Kept from R16: fused k_prep (split_x + prep_w, grid-partitioned).
//      Pipeline: k_prep -> k_gemm_qkv -> k_attn -> k_merge -> k_gemm_o.
// ---------------------------------------------------------------------------

typedef short bf16x8 __attribute__((ext_vector_type(8)));  // 8 bf16 = 4 VGPR
typedef float f32x4  __attribute__((ext_vector_type(4)));

__device__ __forceinline__ short f2bf(float f) {          // RNE
  union { float f; uint32_t u; } a; a.f = f;
  uint32_t r = a.u + 0x7fffu + ((a.u >> 16) & 1u);
  return (short)(r >> 16);
}
__device__ __forceinline__ float bf2f(short s) {
  union { uint32_t u; float f; } a; a.u = ((uint32_t)(uint16_t)s) << 16;
  return a.f;
}
__device__ __forceinline__ uint32_t pack2bf(float a, float b) {  // trunc pack
  union { float f; uint32_t u; } x, y; x.f = a; y.f = b;
  return (x.u >> 16) | (y.u & 0xffff0000u);
}
__device__ __forceinline__ float fast_exp2(float x) {
#if __has_builtin(__builtin_amdgcn_exp2f)
  return __builtin_amdgcn_exp2f(x);
#else
  return exp2f(x);
#endif
}
__device__ __forceinline__ void async16(const void* g, void* l) {
  __builtin_amdgcn_global_load_lds(
      (const __attribute__((address_space(1))) uint32_t*)g,
      (__attribute__((address_space(3))) uint32_t*)l, 16, 0, 0);
}
#define MFMA(a, b, c) __builtin_amdgcn_mfma_f32_16x16x32_bf16((a), (b), (c), 0, 0, 0)

// ---------------------------------------------------------------------------
// 1) fused prep: blocks [0,4096) cast x -> xhi bf16; blocks [4096,5120)
//    transpose W k/n fp32 -> bf16.
// ---------------------------------------------------------------------------
__global__ void k_prep(const float* __restrict__ x, short* __restrict__ xhi,
                       const float* __restrict__ Wq, const float* __restrict__ Wk,
                       const float* __restrict__ Wv, const float* __restrict__ Wo,
                       short* __restrict__ whi, short* __restrict__ wo) {
  __shared__ float T[64][65];
  int bid = blockIdx.x;
  int t = threadIdx.x;
  if (bid < 4096) {
    int i = bid * 256 + t;
    float4 v = ((const float4*)x)[i];
    short4 h;
    h.x = f2bf(v.x);
    h.y = f2bf(v.y);
    h.z = f2bf(v.z);
    h.w = f2bf(v.w);
    ((short4*)xhi)[i] = h;
  } else {
    int i = bid - 4096;
    int bx = i & 15, by = (i >> 4) & 15, z = i >> 8;
    const float* W = (z == 0) ? Wq : (z == 1) ? Wk : (z == 2) ? Wv : Wo;
    int n0 = bx * 64, k0 = by * 64;
    int rr = t >> 4, cc = (t & 15) * 4;
#pragma unroll
    for (int it = 0; it < 4; ++it) {
      int row = rr + it * 16;
      float4 v = *(const float4*)&W[(size_t)(k0 + row) * 1024 + n0 + cc];
      T[row][cc] = v.x; T[row][cc + 1] = v.y; T[row][cc + 2] = v.z; T[row][cc + 3] = v.w;
    }
    __syncthreads();
    short* oh = (z < 3) ? (whi + (size_t)z * 1048576) : wo;
#pragma unroll
    for (int it = 0; it < 4; ++it) {
      int nrow = rr + it * 16;
      short4 h4;
      h4.x = f2bf(T[cc + 0][nrow]);
      h4.y = f2bf(T[cc + 1][nrow]);
      h4.z = f2bf(T[cc + 2][nrow]);
      h4.w = f2bf(T[cc + 3][nrow]);
      *(short4*)&oh[(size_t)(n0 + nrow) * 1024 + k0 + cc] = h4;
    }
  }
}

// ---------------------------------------------------------------------------
// 2) fused QKV projection GEMM (plain bf16, dbuf, single barrier/k-step).
//    Q-proj scaled by LOG2E. Q/K path: operand-swapped MFMA -> short4
//    stores. Q writes hi only; K writes hi+lo. V path writes Vt TRANSPOSED.
// ---------------------------------------------------------------------------
__global__ __launch_bounds__(256, 3) void k_gemm_qkv(
    const short* __restrict__ xhi, const short* __restrict__ whi,
    const float* __restrict__ bq, const float* __restrict__ bk,
    const float* __restrict__ bv,
    short* __restrict__ Qhi, short* __restrict__ Qlo,
    short* __restrict__ Khi, short* __restrict__ Klo,
    short* __restrict__ Vt) {
  __shared__ short AH[2][4096];
  __shared__ short BH[2][4096];
  int tid = threadIdx.x;
  int bx = blockIdx.x;                 // 0..23 ; z = bx>>3 : 0=Q 1=K 2=V
  int m0 = blockIdx.y * 128;
  int n0g = bx * 128;
  int w = tid >> 6, lane = tid & 63, lr = lane & 15, lq = lane >> 4;
  int wm = w >> 1, wn = w & 1;
  int z = bx >> 3;
  f32x4 acc[4][4] = {};

  auto stage = [&](int ks, int pb) {
#pragma unroll
    for (int it = 0; it < 2; ++it) {
      int idx = it * 256 + tid;
      int row = idx >> 2, c = idx & 3;
      int cs = c ^ (row & 3);
      async16(xhi + (size_t)(m0 + row) * 1024 + ks * 32 + cs * 8, &AH[pb][idx * 8]);
      async16(whi + (size_t)(n0g + row) * 1024 + ks * 32 + cs * 8, &BH[pb][idx * 8]);
    }
  };

  stage(0, 0);
  int p = 0;
  int g = lq ^ (lr & 3);
  if (z == 2) {
    // ---- V path: original operand order (row-packed epilogue) ----
    for (int ks = 0; ks < 32; ++ks) {
      __syncthreads();
      if (ks < 31) stage(ks + 1, p ^ 1);
      const bf16x8* A8 = (const bf16x8*)AH[p];
      const bf16x8* B8 = (const bf16x8*)BH[p];
      bf16x8 af[4], bfr[4];
#pragma unroll
      for (int mt = 0; mt < 4; ++mt) af[mt] = A8[(wm * 64 + mt * 16 + lr) * 4 + g];
#pragma unroll
      for (int nt = 0; nt < 4; ++nt) bfr[nt] = B8[(wn * 64 + nt * 16 + lr) * 4 + g];
#pragma unroll
      for (int mt = 0; mt < 4; ++mt)
#pragma unroll
        for (int nt = 0; nt < 4; ++nt)
          acc[mt][nt] = MFMA(af[mt], bfr[nt], acc[mt][nt]);
      p ^= 1;
    }
    // V: write transposed Vt[(b*16+h)*64+dk][s], bias fused, short4 packs
#pragma unroll
    for (int nt = 0; nt < 4; ++nt) {
      int dg = (n0g & 1023) + wn * 64 + nt * 16 + lr;
      float bvv = bv[dg];
      int hh = dg >> 6, dk = dg & 63;
#pragma unroll
      for (int mt = 0; mt < 4; ++mt) {
        int row = m0 + wm * 64 + mt * 16 + lq * 4;
        int b_ = row >> 11, s_ = row & 2047;
        short4 pk;
        pk.x = f2bf(acc[mt][nt][0] + bvv);
        pk.y = f2bf(acc[mt][nt][1] + bvv);
        pk.z = f2bf(acc[mt][nt][2] + bvv);
        pk.w = f2bf(acc[mt][nt][3] + bvv);
        *(short4*)&Vt[(size_t)((b_ * 16 + hh) * 64 + dk) * 2048 + s_] = pk;
      }
    }
  } else {
    // ---- Q/K path: operand-swapped MFMA -> vectorized short4 epilogue ----
    for (int ks = 0; ks < 32; ++ks) {
      __syncthreads();
      if (ks < 31) stage(ks + 1, p ^ 1);
      const bf16x8* A8 = (const bf16x8*)AH[p];
      const bf16x8* B8 = (const bf16x8*)BH[p];
      bf16x8 af[4], bfr[4];
#pragma unroll
      for (int mt = 0; mt < 4; ++mt) af[mt] = A8[(wm * 64 + mt * 16 + lr) * 4 + g];
#pragma unroll
      for (int nt = 0; nt < 4; ++nt) bfr[nt] = B8[(wn * 64 + nt * 16 + lr) * 4 + g];
#pragma unroll
      for (int mt = 0; mt < 4; ++mt)
#pragma unroll
        for (int nt = 0; nt < 4; ++nt)
          acc[mt][nt] = MFMA(bfr[nt], af[mt], acc[mt][nt]);   // D^T fragment
      p ^= 1;
    }
    const float LOG2E = 1.44269504f;
    const float* bias = (z == 0) ? bq : bk;
    short* Ch = (z == 0) ? Qhi : Khi;
    short* Cl = (z == 0) ? Qlo : Klo;
#pragma unroll
    for (int mt = 0; mt < 4; ++mt) {
      int row = m0 + wm * 64 + mt * 16 + lr;
#pragma unroll
      for (int nt = 0; nt < 4; ++nt) {
        int colg = (n0g & 1023) + wn * 64 + nt * 16 + lq * 4;
        float4 b4 = *(const float4*)&bias[colg];
        float v0 = acc[mt][nt][0] + b4.x;
        float v1 = acc[mt][nt][1] + b4.y;
        float v2 = acc[mt][nt][2] + b4.z;
        float v3 = acc[mt][nt][3] + b4.w;
        if (z == 0) { v0 *= LOG2E; v1 *= LOG2E; v2 *= LOG2E; v3 *= LOG2E; }
        short4 hi4, lo4;
        hi4.x = f2bf(v0); lo4.x = f2bf(v0 - bf2f(hi4.x));
        hi4.y = f2bf(v1); lo4.y = f2bf(v1 - bf2f(hi4.y));
        hi4.z = f2bf(v2); lo4.z = f2bf(v2 - bf2f(hi4.z));
        hi4.w = f2bf(v3); lo4.w = f2bf(v3 - bf2f(hi4.w));
        size_t o = (size_t)row * 1024 + colg;
        *(short4*)&Ch[o] = hi4;
        if (z == 1) *(short4*)&Cl[o] = lo4;   // Qlo not needed
      }
    }
  }
}

// ---------------------------------------------------------------------------
// 3) O-projection GEMM: out = Obuf @ Wo^T + bo, fp32 out.
//    128x128 tiles, m97 structure; operand-swapped MFMA -> float4 stores.
// ---------------------------------------------------------------------------
__global__ __launch_bounds__(256, 3) void k_gemm_o(
    const short* __restrict__ Ab, const short* __restrict__ Bb,
    const float* __restrict__ bias, float* __restrict__ Cf) {
  __shared__ short AH[2][4096];
  __shared__ short BH[2][4096];
  int tid = threadIdx.x;
  int m0 = blockIdx.y * 128, n0 = blockIdx.x * 128;
  int w = tid >> 6, lane = tid & 63, lr = lane & 15, lq = lane >> 4;
  int wm = w >> 1, wn = w & 1;
  f32x4 acc[4][4] = {};

  auto stage = [&](int ks, int pb) {
#pragma unroll
    for (int it = 0; it < 2; ++it) {
      int idx = it * 256 + tid;
      int row = idx >> 2, c = idx & 3;
      int cs = c ^ (row & 3);
      async16(Ab + (size_t)(m0 + row) * 1024 + ks * 32 + cs * 8, &AH[pb][idx * 8]);
      async16(Bb + (size_t)(n0 + row) * 1024 + ks * 32 + cs * 8, &BH[pb][idx * 8]);
    }
  };

  stage(0, 0);
  int p = 0;
  int g = lq ^ (lr & 3);
  for (int ks = 0; ks < 32; ++ks) {
    __syncthreads();
    if (ks < 31) stage(ks + 1, p ^ 1);
    const bf16x8* A8 = (const bf16x8*)AH[p];
    const bf16x8* B8 = (const bf16x8*)BH[p];
    bf16x8 af[4], bfr[4];
#pragma unroll
    for (int mt = 0; mt < 4; ++mt) af[mt] = A8[(wm * 64 + mt * 16 + lr) * 4 + g];
#pragma unroll
    for (int nt = 0; nt < 4; ++nt) bfr[nt] = B8[(wn * 64 + nt * 16 + lr) * 4 + g];
#pragma unroll
    for (int mt = 0; mt < 4; ++mt)
#pragma unroll
      for (int nt = 0; nt < 4; ++nt)
        acc[mt][nt] = MFMA(bfr[nt], af[mt], acc[mt][nt]);     // D^T fragment
    p ^= 1;
  }

#pragma unroll
  for (int mt = 0; mt < 4; ++mt) {
    int row = m0 + wm * 64 + mt * 16 + lr;
#pragma unroll
    for (int nt = 0; nt < 4; ++nt) {
      int colg = n0 + wn * 64 + nt * 16 + lq * 4;
      float4 b4 = *(const float4*)&bias[colg];
      float4 o4;
      o4.x = acc[mt][nt][0] + b4.x;
      o4.y = acc[mt][nt][1] + b4.y;
      o4.z = acc[mt][nt][2] + b4.z;
      o4.w = acc[mt][nt][3] + b4.w;
      *(float4*)&Cf[(size_t)row * 1024 + colg] = o4;
    }
  }
}

// ---------------------------------------------------------------------------
// 4) flash attention, split-K chunked (R15 epilogue: plain partial write,
//    merge in separate kernel). Work item o (0..47) per bh:
//    o<16:            chunk0 of pair P=16+o, tiles [0,16), partial slot A.
//    o>=16, q=o-16:   lvl=q>>1 (trips 16-lvl);
//      q odd:  single pair P=15-lvl, tiles [0,P+1), direct output.
//      q even: chunk1 of pair P=31-lvl, tiles [16,P+1), partial slot B.
//    All trips <=16; 1536 blocks -> 6/CU queue, phase diversity.
// ---------------------------------------------------------------------------
__global__ __launch_bounds__(256, 4) void k_attn(
    const short* __restrict__ Khi, const short* __restrict__ Klo,
    const short* __restrict__ Qhi, const short* __restrict__ Vt,
    const int* __restrict__ amask, short* __restrict__ Obuf,
    float* __restrict__ PA, float* __restrict__ PB,
    float* __restrict__ LA, float* __restrict__ LB) {
  __shared__ short QH[2][4096];     // Q-proj tile hi: [j 64][d 64] swizzled
  __shared__ short VS[2][4096];     // V^T tile: [d 64][j 64] swizzled
  int tid = threadIdx.x;
  int bid = blockIdx.x;             // 0..1535
  int xcd = bid & 7, i2 = bid >> 3; // i2: 0..191
  int bh = xcd * 4 + (i2 & 3);      // 4 heads per XCD for L2 locality
  int o  = i2 >> 2;                 // work item 0..47 (LPT order)
  int P, t0, t1;
  bool partial, slotB = false;
  if (o < 16) {                     // chunk0, trips 16
    P = 16 + o; t0 = 0; t1 = 16; partial = true;
  } else {
    int q = o - 16, lvl = q >> 1;   // trips = 16 - lvl
    if (q & 1) {                    // single chunk, direct
      P = 15 - lvl; t0 = 0; t1 = P + 1; partial = false;
    } else {                        // chunk1
      P = 31 - lvl; t0 = 16; t1 = P + 1; partial = true; slotB = true;
    }
  }
  int b = bh >> 4, h = bh & 15;
  int w = tid >> 6, lane = tid & 63, lr = lane & 15, lq = lane >> 4;
  int band = 2 * P + (w >> 1);
  int rb0 = band * 32 + (w & 1) * 16;   // wave's 16-row chunk base (in s)

  // keys-role B-fragments (K-proj rows of this wave's chunk), hi+lo
  bf16x8 kh[2], kl[2];
  {
    size_t ra = ((size_t)(b * 2048 + rb0 + lr)) * 1024 + h * 64;
#pragma unroll
    for (int ks = 0; ks < 2; ++ks) {
      kh[ks] = *(const bf16x8*)(Khi + ra + ks * 32 + lq * 8);
      kl[ks] = *(const bf16x8*)(Klo + ra + ks * 32 + lq * 8);
    }
  }

  f32x4 O[4] = {};
  float ls = 0.f;
  int iq = rb0 + lr;                // this lane's query row (s index)
  int baddr0 = (((lq & 1) * 2) * 16 + lr) * 4;   // bpermute byte addrs
  int baddr1 = baddr0 + 64;

  auto stage = [&](int jt, int pb) {
    int j0 = jt * 64;
#pragma unroll
    for (int it = 0; it < 2; ++it) {
      int idx2 = it * 256 + tid;    // 0..511
      int rr = idx2 >> 3, c = idx2 & 7;
      int cs = c ^ (rr & 7);
      size_t gq = ((size_t)(b * 2048 + j0 + rr)) * 1024 + h * 64 + cs * 8;
      async16(Qhi + gq, &QH[pb][idx2 * 8]);
      size_t gv = ((size_t)(bh * 64 + rr)) * 2048 + j0 + cs * 8;
      async16(Vt + gv, &VS[pb][idx2 * 8]);
    }
  };

  stage(t0, 0);
  int p = 0;
  for (int t = t0; t < t1; ++t) {
    __syncthreads();                // buf p staged; buf p^1 free
    if (t + 1 < t1) stage(t + 1, p ^ 1);
    int j0 = t * 64;
    const bf16x8* Q8 = (const bf16x8*)QH[p];
    const bf16x8* V8 = (const bf16x8*)VS[p];

    // padding-mask fast path (wave-level)
    int av = amask[b * 2048 + j0 + lane];
    unsigned long long bal = __ballot(av != 0);
    bool allv = (bal == ~0ull);

    // ---- S^T: rows j (4 mt), cols q (lr). 2-term split. ----
    f32x4 s[4] = {};
#pragma unroll
    for (int mt = 0; mt < 4; ++mt) {
      int row = mt * 16 + lr;
#pragma unroll
      for (int ks = 0; ks < 2; ++ks) {
        int gi = row * 8 + ((ks * 4 + lq) ^ (row & 7));
        bf16x8 qa = Q8[gi];
        s[mt] = MFMA(qa, kh[ks], s[mt]);
        s[mt] = MFMA(qa, kl[ks], s[mt]);
      }
    }

    // ---- exp2 / masks / rowsum / pack ----
    bool diag = (t == P);           // pair's last tile (never true in chunk0)
    float pv[4][4];
#pragma unroll
    for (int mt = 0; mt < 4; ++mt)
#pragma unroll
      for (int r = 0; r < 4; ++r)
        pv[mt][r] = fast_exp2(s[mt][r]);
    if (diag) {
#pragma unroll
      for (int mt = 0; mt < 4; ++mt)
#pragma unroll
        for (int r = 0; r < 4; ++r)
          if (j0 + mt * 16 + lq * 4 + r > iq) pv[mt][r] = 0.f;
    }
    if (!allv) {
#pragma unroll
      for (int mt = 0; mt < 4; ++mt)
#pragma unroll
        for (int r = 0; r < 4; ++r)
          if (!((bal >> (mt * 16 + lq * 4 + r)) & 1)) pv[mt][r] = 0.f;
    }
    uint32_t pd[4][2];
#pragma unroll
    for (int mt = 0; mt < 4; ++mt) {
      ls += (pv[mt][0] + pv[mt][1]) + (pv[mt][2] + pv[mt][3]);
      pd[mt][0] = pack2bf(pv[mt][0], pv[mt][1]);
      pd[mt][1] = pack2bf(pv[mt][2], pv[mt][3]);
    }

    // ---- P^T -> A-frag via bpermute; PV ----
#pragma unroll
    for (int k2 = 0; k2 < 2; ++k2) {
      union { int i[4]; bf16x8 v; } pa;
#pragma unroll
      for (int dd = 0; dd < 4; ++dd) {
        int addr = (dd >> 1) ? baddr1 : baddr0;
        int v0 = __builtin_amdgcn_ds_bpermute(addr, (int)pd[k2 * 2 + 0][dd & 1]);
        int v1 = __builtin_amdgcn_ds_bpermute(addr, (int)pd[k2 * 2 + 1][dd & 1]);
        pa.i[dd] = (lq >> 1) ? v1 : v0;
      }
#pragma unroll
      for (int nt = 0; nt < 4; ++nt) {
        int row = nt * 16 + lr;
        bf16x8 vb = V8[row * 8 + ((k2 * 4 + lq) ^ (row & 7))];
        O[nt] = MFMA(pa.v, vb, O[nt]);
      }
    }
    p ^= 1;
  }

  // ---- epilogue: reduce rowsum over lq ----
  float tsum = ls;
  tsum += __shfl_xor(tsum, 16);
  tsum += __shfl_xor(tsum, 32);     // lane l: full rowsum of row rb0+(l&15)

  if (!partial) {
    float inv[4];
#pragma unroll
    for (int r = 0; r < 4; ++r) inv[r] = 1.0f / __shfl(tsum, lq * 4 + r, 64);
#pragma unroll
    for (int nt = 0; nt < 4; ++nt)
#pragma unroll
      for (int r = 0; r < 4; ++r) {
        int row = b * 2048 + rb0 + lq * 4 + r;
        int col = h * 64 + nt * 16 + lr;
        Obuf[(size_t)row * 1024 + col] = f2bf(O[nt][r] * inv[r]);
      }
  } else {
    // unnormalized fp32 partial: rows pr = bh*1024 + (P-16)*64 + w*16 + 0..15
    float* PO = slotB ? PB : PA;
    float* PL = slotB ? LB : LA;
    int prb = bh * 1024 + (P - 16) * 64 + w * 16;
#pragma unroll
    for (int nt = 0; nt < 4; ++nt)
#pragma unroll
      for (int r = 0; r < 4; ++r)
        PO[(size_t)(prb + lq * 4 + r) * 64 + nt * 16 + lr] = O[nt][r];
    if (lq == 0) PL[prb + lr] = tsum;
  }
}

// ---------------------------------------------------------------------------
// 4b) merge split-K partials: O = (PA+PB)/(LA+LB) -> Obuf (bf16).
//     32768 rows x 64 cols; thread = (row, float4 col-group).
// ---------------------------------------------------------------------------
__global__ void k_merge(const float* __restrict__ PA, const float* __restrict__ PB,
                        const float* __restrict__ LA, const float* __restrict__ LB,
                        short* __restrict__ Obuf) {
  int t = blockIdx.x * 256 + threadIdx.x;   // 0..524287
  int pr = t >> 4, cg = t & 15;
  float4 a = ((const float4*)PA)[pr * 16 + cg];
  float4 bb4 = ((const float4*)PB)[pr * 16 + cg];
  float inv = 1.0f / (LA[pr] + LB[pr]);
  int bh = pr >> 10, P = 16 + ((pr >> 6) & 15), loc = pr & 63;
  int b = bh >> 4, h = bh & 15;
  size_t addr = ((size_t)(b * 2048 + P * 64 + loc)) * 1024 + h * 64 + cg * 4;
  short4 oq;
  oq.x = f2bf((a.x + bb4.x) * inv);
  oq.y = f2bf((a.y + bb4.y) * inv);
  oq.z = f2bf((a.z + bb4.z) * inv);
  oq.w = f2bf((a.w + bb4.w) * inv);
  *(short4*)&Obuf[addr] = oq;
}

// ---------------------------------------------------------------------------
// launcher
// ---------------------------------------------------------------------------
extern "C" void kernel_launch(void* const* d_in, const int* in_sizes, int n_in,
                              void* d_out, int out_size, void* d_ws, size_t ws_size,
                              hipStream_t stream) {
  const float* x  = (const float*)d_in[0];
  const int* amask = (const int*)d_in[1];
  const float* Wq = (const float*)d_in[2];
  const float* bq = (const float*)d_in[3];
  const float* Wk = (const float*)d_in[4];
  const float* bk = (const float*)d_in[5];
  const float* Wv = (const float*)d_in[6];
  const float* bv = (const float*)d_in[7];
  const float* Wo = (const float*)d_in[8];
  const float* bo = (const float*)d_in[9];

  char* ws = (char*)d_ws;
  const size_t MB = 1024 * 1024;
  short* xhi = (short*)(ws);             // 0..8MB; dead after qkv -> Obuf
  float* PA  = (float*)(ws + 8 * MB);    // 8..16MB: split-K partial O slot A
  short* whi = (short*)(ws + 16 * MB);   // 16..22 (q,k,v)
  float* LA  = (float*)(ws + 22 * MB);   // rowsum A (128KB)
  float* LB  = (float*)(ws + 23 * MB);   // rowsum B (128KB)
  short* wo  = (short*)(ws + 26 * MB);   // 26..28
  short* Qhi = (short*)(ws + 28 * MB);
  float* PB  = (float*)(ws + 36 * MB);   // 36..44MB (dead Qlo region): slot B
  short* Qlo = (short*)(ws + 36 * MB);   // unused (kept for qkv signature)
  short* Khi = (short*)(ws + 44 * MB);
  short* Klo = (short*)(ws + 52 * MB);
  short* Vt  = (short*)(ws + 60 * MB);   // total 68MB
  short* Obuf = xhi;                     // xhi dead after qkv

  k_prep<<<5120, 256, 0, stream>>>(x, xhi, Wq, Wk, Wv, Wo, whi, wo);
  k_gemm_qkv<<<dim3(24, 32), 256, 0, stream>>>(xhi, whi, bq, bk, bv,
                                               Qhi, Qlo, Khi, Klo, Vt);
  k_attn<<<1536, 256, 0, stream>>>(Khi, Klo, Qhi, Vt, amask, Obuf,
                                   PA, PB, LA, LB);
  k_merge<<<2048, 256, 0, stream>>>(PA, PB, LA, LB, Obuf);
  k_gemm_o<<<dim3(8, 32), 256, 0, stream>>>(Obuf, wo, bo, (float*)d_out);
}